// Round 3
// baseline (116.252 us; speedup 1.0000x reference)
//
#include <hip/hip_runtime.h>
#include <float.h>
#include <stdint.h>

// CorrLoss via bf16 MFMA, symmetric (triangular-tile) Gram:
//   k0: cast feat fp32 -> bf16 (RNE) into ws
//   k1: 528 upper-tri 128x128 tiles; each tile feeds BOTH the direct (rows of
//       bi, slice bj) and transposed (rows of bj, slice bi) masked min/max.
//       part[s][row] has exactly one writer per cell -> no atomics.
//   k2: single-block fold: 32 slices -> relu(an-ap+40) -> mean -> out[0]
//       (no memset, no atomic).

#define N_ROWS 4096
#define D_K    512
#define BM     128
#define BN     128
#define BK     32
#define NTB    32                // 4096/128 tile-blocks per dim
#define NTILES (NTB * (NTB + 1) / 2)   // 528
#define MARGIN 40.0f

typedef __bf16 bf16_t;
typedef bf16_t bf16x8 __attribute__((ext_vector_type(8)));
typedef float  floatx4 __attribute__((ext_vector_type(4)));
typedef unsigned short ushort_t;
typedef ushort_t ushortx8 __attribute__((ext_vector_type(8)));

#define GLOAD_LDS16(g, l)                                        \
    __builtin_amdgcn_global_load_lds(                            \
        (const __attribute__((address_space(1))) void*)(g),      \
        (__attribute__((address_space(3))) void*)(l), 16, 0, 0)

__device__ __forceinline__ ushort_t f2bf_rne(float x) {
    uint32_t u = __builtin_bit_cast(uint32_t, x);
    return (ushort_t)((u + 0x7FFFu + ((u >> 16) & 1u)) >> 16);
}

__global__ __launch_bounds__(256) void cast_kernel(
    const float* __restrict__ f, ushort_t* __restrict__ o)
{
    const int i = (blockIdx.x * 256 + threadIdx.x) * 8;
    const float4 v0 = *(const float4*)(f + i);
    const float4 v1 = *(const float4*)(f + i + 4);
    ushortx8 r;
    r[0] = f2bf_rne(v0.x); r[1] = f2bf_rne(v0.y);
    r[2] = f2bf_rne(v0.z); r[3] = f2bf_rne(v0.w);
    r[4] = f2bf_rne(v1.x); r[5] = f2bf_rne(v1.y);
    r[6] = f2bf_rne(v1.z); r[7] = f2bf_rne(v1.w);
    *(ushortx8*)(o + i) = r;
}

__global__ __launch_bounds__(256) void gram_mfma_kernel(
    const ushort_t* __restrict__ fb, const int* __restrict__ tgt,
    float* __restrict__ ap_part, float* __restrict__ an_part)
{
    __shared__ __align__(16) ushort_t As[BM * BK];   // 8 KB, [row][k] row-major
    __shared__ __align__(16) ushort_t Bs[BN * BK];   // 8 KB
    __shared__ int tgI[BM];
    __shared__ int tgJ[BN];
    __shared__ float apRed[2][BM],  anRed[2][BM];    // direct, indexed by wc
    __shared__ float apRedT[2][BN], anRedT[2][BN];   // transposed, indexed by wr

    // flat block id -> upper-tri (bi, bj), row-major
    int bi = 0, rem = blockIdx.x;
    while (rem >= NTB - bi) { rem -= NTB - bi; ++bi; }
    const int bj = bi + rem;

    const int tid  = threadIdx.x;
    const int i0   = bi * BM;
    const int j0   = bj * BN;
    const int lane = tid & 63;
    const int wave = tid >> 6;
    const int wr   = wave >> 1;      // wave row half (0/1)
    const int wc   = wave & 1;       // wave col half (0/1)
    const int lr   = lane & 15;      // col within 16-tile (C/D) / row (A,B frag)
    const int lg   = lane >> 4;      // k-group (A,B) / row-quad (C/D)

    if (tid < BM)            tgI[tid]      = tgt[i0 + tid];
    else if (tid < BM + BN)  tgJ[tid - BM] = tgt[j0 + tid - BM];

    // staging: thread t loads 16 B = 8 bf16 of tile-row (t>>2), k-quad (t&3)
    const int srow = tid >> 2;
    const int skq  = tid & 3;
    const size_t gA0 = (size_t)(i0 + srow) * D_K + skq * 8;
    const size_t gB0 = (size_t)(j0 + srow) * D_K + skq * 8;
    char* AsB = (char*)As;
    char* BsB = (char*)Bs;

    floatx4 acc[4][4];
#pragma unroll
    for (int a = 0; a < 4; ++a)
#pragma unroll
        for (int b = 0; b < 4; ++b) acc[a][b] = (floatx4)0.0f;

    for (int k0 = 0; k0 < D_K; k0 += BK) {
        GLOAD_LDS16(fb + gA0 + k0,            AsB + tid * 16);
        GLOAD_LDS16(fb + gA0 + k0 + 64 * D_K, AsB + 4096 + tid * 16);
        GLOAD_LDS16(fb + gB0 + k0,            BsB + tid * 16);
        GLOAD_LDS16(fb + gB0 + k0 + 64 * D_K, BsB + 4096 + tid * 16);
        __syncthreads();

        bf16x8 af[4], bf[4];
#pragma unroll
        for (int rg = 0; rg < 4; ++rg)
            af[rg] = *(const bf16x8*)(As + ((wr * 64 + rg * 16 + lr) * BK + lg * 8));
#pragma unroll
        for (int cg = 0; cg < 4; ++cg)
            bf[cg] = *(const bf16x8*)(Bs + ((wc * 64 + cg * 16 + lr) * BK + lg * 8));
#pragma unroll
        for (int rg = 0; rg < 4; ++rg)
#pragma unroll
            for (int cg = 0; cg < 4; ++cg)
                acc[rg][cg] = __builtin_amdgcn_mfma_f32_16x16x32_bf16(
                    af[rg], bf[cg], acc[rg][cg], 0, 0, 0);
        __syncthreads();
    }

    // ---- epilogue ----
    // C/D layout per 16x16 fragment: col = lr, row = lg*4 + reg
    int tj[4];
#pragma unroll
    for (int cg = 0; cg < 4; ++cg) tj[cg] = tgJ[wc * 64 + cg * 16 + lr];

    float apT[4], anT[4];            // transposed accum, per cg (this lane's col)
#pragma unroll
    for (int cg = 0; cg < 4; ++cg) { apT[cg] = FLT_MAX; anT[cg] = -FLT_MAX; }

#pragma unroll
    for (int rg = 0; rg < 4; ++rg) {
#pragma unroll
        for (int r = 0; r < 4; ++r) {
            const int rloc = wr * 64 + rg * 16 + lg * 4 + r;
            const int ti = tgI[rloc];
            float vap = FLT_MAX, van = -FLT_MAX;
#pragma unroll
            for (int cg = 0; cg < 4; ++cg) {
                const float v = acc[rg][cg][r];
                if (ti == tj[cg]) { vap = fminf(vap, v); apT[cg] = fminf(apT[cg], v); }
                else              { van = fmaxf(van, v); anT[cg] = fmaxf(anT[cg], v); }
            }
            // direct: reduce over the 16 cols held by lanes lr=0..15
#pragma unroll
            for (int m = 1; m < 16; m <<= 1) {
                vap = fminf(vap, __shfl_xor(vap, m));
                van = fmaxf(van, __shfl_xor(van, m));
            }
            if (lr == 0) { apRed[wc][rloc] = vap; anRed[wc][rloc] = van; }
        }
    }
    // transposed: reduce over the 4 lane-groups (rows lg*4+r already folded)
#pragma unroll
    for (int cg = 0; cg < 4; ++cg) {
        float vap = apT[cg], van = anT[cg];
        vap = fminf(vap, __shfl_xor(vap, 16)); van = fmaxf(van, __shfl_xor(van, 16));
        vap = fminf(vap, __shfl_xor(vap, 32)); van = fmaxf(van, __shfl_xor(van, 32));
        if (lg == 0) {
            apRedT[wr][wc * 64 + cg * 16 + lr] = vap;
            anRedT[wr][wc * 64 + cg * 16 + lr] = van;
        }
    }
    __syncthreads();

    if (tid < BM) {
        ap_part[(size_t)bj * N_ROWS + i0 + tid] = fminf(apRed[0][tid], apRed[1][tid]);
        an_part[(size_t)bj * N_ROWS + i0 + tid] = fmaxf(anRed[0][tid], anRed[1][tid]);
        if (bi != bj) {
            ap_part[(size_t)bi * N_ROWS + j0 + tid] = fminf(apRedT[0][tid], apRedT[1][tid]);
            an_part[(size_t)bi * N_ROWS + j0 + tid] = fmaxf(anRedT[0][tid], anRedT[1][tid]);
        }
    }
}

__global__ __launch_bounds__(1024) void fold_kernel(
    const float* __restrict__ ap_part, const float* __restrict__ an_part,
    float* __restrict__ out)
{
    __shared__ float sred[16];
    const int tid = threadIdx.x;
    float local = 0.0f;
    for (int row = tid; row < N_ROWS; row += 1024) {
        float ap = FLT_MAX, an = -FLT_MAX;
#pragma unroll
        for (int js = 0; js < NTB; ++js) {
            ap = fminf(ap, ap_part[(size_t)js * N_ROWS + row]);
            an = fmaxf(an, an_part[(size_t)js * N_ROWS + row]);
        }
        const float v = an - ap + MARGIN;
        local += (v > 0.0f) ? v : 0.0f;
    }
#pragma unroll
    for (int m = 32; m >= 1; m >>= 1) local += __shfl_down(local, m);
    if ((tid & 63) == 0) sred[tid >> 6] = local;
    __syncthreads();
    if (tid == 0) {
        float s = 0.0f;
#pragma unroll
        for (int w = 0; w < 16; ++w) s += sred[w];
        out[0] = s * (1.0f / N_ROWS);
    }
}

extern "C" void kernel_launch(void* const* d_in, const int* in_sizes, int n_in,
                              void* d_out, int out_size, void* d_ws, size_t ws_size,
                              hipStream_t stream)
{
    const float* feat = (const float*)d_in[0];
    const int*   tgt  = (const int*)d_in[1];

    ushort_t* fb      = (ushort_t*)d_ws;                       // 4 MB bf16 feat
    float*    ap_part = (float*)(fb + (size_t)N_ROWS * D_K);   // 32*4096 floats
    float*    an_part = ap_part + (size_t)NTB * N_ROWS;        // 32*4096 floats

    cast_kernel<<<(N_ROWS * D_K) / (256 * 8), 256, 0, stream>>>(feat, fb);
    gram_mfma_kernel<<<NTILES, 256, 0, stream>>>(fb, tgt, ap_part, an_part);
    fold_kernel<<<1, 1024, 0, stream>>>(ap_part, an_part, (float*)d_out);
}

// Round 4
// 114.407 us; speedup vs baseline: 1.0161x; 1.0161x over previous
//
#include <hip/hip_runtime.h>
#include <float.h>
#include <stdint.h>

// CorrLoss via bf16 MFMA, symmetric tiles, 2 dispatches:
//   k0: cast feat fp32 -> bf16 (RNE) into ws; init monotone-key min/max arrays
//       (ap=0xFFFFFFFF, an=0x0) and the done-counter.
//   k1: 528 upper-tri 128x128 tiles; per-row masked min/max folded via
//       device-scope atomicMin/atomicMax on order-preserving uint keys
//       (coherence-point ops -> no cross-XCD staleness, no partial arrays).
//       Last finishing block (threadfence + counter) reads the 32 KB of keys,
//       computes mean(relu(an-ap+40)) -> out[0]. No separate fold dispatch.

#define N_ROWS 4096
#define D_K    512
#define BM     128
#define BN     128
#define BK     32
#define NTB    32                       // 4096/128
#define NTILES (NTB * (NTB + 1) / 2)    // 528
#define MARGIN 40.0f

typedef __bf16 bf16_t;
typedef bf16_t bf16x8 __attribute__((ext_vector_type(8)));
typedef float  floatx4 __attribute__((ext_vector_type(4)));
typedef unsigned short ushort_t;
typedef ushort_t ushortx8 __attribute__((ext_vector_type(8)));

#define GLOAD_LDS16(g, l)                                        \
    __builtin_amdgcn_global_load_lds(                            \
        (const __attribute__((address_space(1))) void*)(g),      \
        (__attribute__((address_space(3))) void*)(l), 16, 0, 0)

__device__ __forceinline__ ushort_t f2bf_rne(float x) {
    uint32_t u = __builtin_bit_cast(uint32_t, x);
    return (ushort_t)((u + 0x7FFFu + ((u >> 16) & 1u)) >> 16);
}

// order-preserving float <-> uint key (larger float => larger key)
__device__ __forceinline__ unsigned fkey(float f) {
    unsigned u = __builtin_bit_cast(unsigned, f);
    return (u & 0x80000000u) ? ~u : (u | 0x80000000u);
}
__device__ __forceinline__ float funkey(unsigned k) {
    unsigned u = (k & 0x80000000u) ? (k & 0x7FFFFFFFu) : ~k;
    return __builtin_bit_cast(float, u);
}

__global__ __launch_bounds__(256) void cast_kernel(
    const float* __restrict__ f, ushort_t* __restrict__ o,
    unsigned* __restrict__ ap_key, unsigned* __restrict__ an_key,
    int* __restrict__ counter)
{
    const int gid = blockIdx.x * 256 + threadIdx.x;
    if (gid < N_ROWS) { ap_key[gid] = 0xFFFFFFFFu; an_key[gid] = 0u; }
    if (gid == 0) *counter = 0;

    const int i = gid * 8;
    const float4 v0 = *(const float4*)(f + i);
    const float4 v1 = *(const float4*)(f + i + 4);
    ushortx8 r;
    r[0] = f2bf_rne(v0.x); r[1] = f2bf_rne(v0.y);
    r[2] = f2bf_rne(v0.z); r[3] = f2bf_rne(v0.w);
    r[4] = f2bf_rne(v1.x); r[5] = f2bf_rne(v1.y);
    r[6] = f2bf_rne(v1.z); r[7] = f2bf_rne(v1.w);
    *(ushortx8*)(o + i) = r;
}

__global__ __launch_bounds__(256) void gram_mfma_kernel(
    const ushort_t* __restrict__ fb, const int* __restrict__ tgt,
    unsigned* __restrict__ ap_key, unsigned* __restrict__ an_key,
    int* __restrict__ counter, float* __restrict__ out)
{
    __shared__ __align__(16) ushort_t As[BM * BK];   // 8 KB, [row][k]
    __shared__ __align__(16) ushort_t Bs[BN * BK];   // 8 KB
    __shared__ int tgI[BM];
    __shared__ int tgJ[BN];
    __shared__ float sred[4];
    __shared__ int lastFlag;

    // flat block id -> upper-tri (bi, bj), row-major
    int bi = 0, rem = blockIdx.x;
    while (rem >= NTB - bi) { rem -= NTB - bi; ++bi; }
    const int bj = bi + rem;

    const int tid  = threadIdx.x;
    const int i0   = bi * BM;
    const int j0   = bj * BN;
    const int lane = tid & 63;
    const int wave = tid >> 6;
    const int wr   = wave >> 1;
    const int wc   = wave & 1;
    const int lr   = lane & 15;
    const int lg   = lane >> 4;

    if (tid < BM)            tgI[tid]      = tgt[i0 + tid];
    else if (tid < BM + BN)  tgJ[tid - BM] = tgt[j0 + tid - BM];

    const int srow = tid >> 2;
    const int skq  = tid & 3;
    const size_t gA0 = (size_t)(i0 + srow) * D_K + skq * 8;
    const size_t gB0 = (size_t)(j0 + srow) * D_K + skq * 8;
    char* AsB = (char*)As;
    char* BsB = (char*)Bs;

    floatx4 acc[4][4];
#pragma unroll
    for (int a = 0; a < 4; ++a)
#pragma unroll
        for (int b = 0; b < 4; ++b) acc[a][b] = (floatx4)0.0f;

    for (int k0 = 0; k0 < D_K; k0 += BK) {
        GLOAD_LDS16(fb + gA0 + k0,            AsB + tid * 16);
        GLOAD_LDS16(fb + gA0 + k0 + 64 * D_K, AsB + 4096 + tid * 16);
        GLOAD_LDS16(fb + gB0 + k0,            BsB + tid * 16);
        GLOAD_LDS16(fb + gB0 + k0 + 64 * D_K, BsB + 4096 + tid * 16);
        __syncthreads();

        bf16x8 af[4], bf[4];
#pragma unroll
        for (int rg = 0; rg < 4; ++rg)
            af[rg] = *(const bf16x8*)(As + ((wr * 64 + rg * 16 + lr) * BK + lg * 8));
#pragma unroll
        for (int cg = 0; cg < 4; ++cg)
            bf[cg] = *(const bf16x8*)(Bs + ((wc * 64 + cg * 16 + lr) * BK + lg * 8));
#pragma unroll
        for (int rg = 0; rg < 4; ++rg)
#pragma unroll
            for (int cg = 0; cg < 4; ++cg)
                acc[rg][cg] = __builtin_amdgcn_mfma_f32_16x16x32_bf16(
                    af[rg], bf[cg], acc[rg][cg], 0, 0, 0);
        __syncthreads();
    }

    // ---- epilogue: C/D layout per 16x16 frag: col = lr, row = lg*4 + reg ----
    int tj[4];
#pragma unroll
    for (int cg = 0; cg < 4; ++cg) tj[cg] = tgJ[wc * 64 + cg * 16 + lr];

    float apT[4], anT[4];
#pragma unroll
    for (int cg = 0; cg < 4; ++cg) { apT[cg] = FLT_MAX; anT[cg] = -FLT_MAX; }

#pragma unroll
    for (int rg = 0; rg < 4; ++rg) {
#pragma unroll
        for (int r = 0; r < 4; ++r) {
            const int rloc = wr * 64 + rg * 16 + lg * 4 + r;
            const int ti = tgI[rloc];
            float vap = FLT_MAX, van = -FLT_MAX;
#pragma unroll
            for (int cg = 0; cg < 4; ++cg) {
                const float v = acc[rg][cg][r];
                if (ti == tj[cg]) { vap = fminf(vap, v); apT[cg] = fminf(apT[cg], v); }
                else              { van = fmaxf(van, v); anT[cg] = fmaxf(anT[cg], v); }
            }
#pragma unroll
            for (int m = 1; m < 16; m <<= 1) {
                vap = fminf(vap, __shfl_xor(vap, m));
                van = fmaxf(van, __shfl_xor(van, m));
            }
            if (lr == 0) {   // lanes 0,16,32,48 -> 4 distinct rows
                atomicMin(&ap_key[i0 + rloc], fkey(vap));
                atomicMax(&an_key[i0 + rloc], fkey(van));
            }
        }
    }
    if (bi != bj) {
#pragma unroll
        for (int cg = 0; cg < 4; ++cg) {
            float vap = apT[cg], van = anT[cg];
            vap = fminf(vap, __shfl_xor(vap, 16)); van = fmaxf(van, __shfl_xor(van, 16));
            vap = fminf(vap, __shfl_xor(vap, 32)); van = fmaxf(van, __shfl_xor(van, 32));
            if (lg == 0) {   // lanes 0..15 -> 16 distinct cols
                atomicMin(&ap_key[j0 + wc * 64 + cg * 16 + lr], fkey(vap));
                atomicMax(&an_key[j0 + wc * 64 + cg * 16 + lr], fkey(van));
            }
        }
    }

    // ---- last-block fold ----
    __threadfence();
    __syncthreads();
    if (tid == 0) lastFlag = (atomicAdd(counter, 1) == NTILES - 1);
    __syncthreads();
    if (!lastFlag) return;

    __threadfence();
    float local = 0.0f;
    for (int r = tid; r < N_ROWS; r += 256) {
        const float ap = funkey(ap_key[r]);
        const float an = funkey(an_key[r]);
        const float v = an - ap + MARGIN;
        local += (v > 0.0f) ? v : 0.0f;
    }
#pragma unroll
    for (int m = 32; m >= 1; m >>= 1) local += __shfl_down(local, m);
    if (lane == 0) sred[wave] = local;
    __syncthreads();
    if (tid == 0)
        out[0] = (sred[0] + sred[1] + sred[2] + sred[3]) * (1.0f / N_ROWS);
}

extern "C" void kernel_launch(void* const* d_in, const int* in_sizes, int n_in,
                              void* d_out, int out_size, void* d_ws, size_t ws_size,
                              hipStream_t stream)
{
    const float* feat = (const float*)d_in[0];
    const int*   tgt  = (const int*)d_in[1];

    ushort_t* fb      = (ushort_t*)d_ws;                        // 4 MB bf16 feat
    unsigned* ap_key  = (unsigned*)(fb + (size_t)N_ROWS * D_K); // 16 KB
    unsigned* an_key  = ap_key + N_ROWS;                        // 16 KB
    int*      counter = (int*)(an_key + N_ROWS);

    cast_kernel<<<(N_ROWS * D_K) / (256 * 8), 256, 0, stream>>>(
        feat, fb, ap_key, an_key, counter);
    gram_mfma_kernel<<<NTILES, 256, 0, stream>>>(
        fb, tgt, ap_key, an_key, counter, (float*)d_out);
}